// Round 13
// baseline (274.645 us; speedup 1.0000x reference)
//
#include <hip/hip_runtime.h>
#include <hip/hip_bf16.h>

#define N_NODES 50000
#define N_EDGES 800000
#define F 128
#define L 64
#define BN_EPS 1e-5f
#define SCAN_BLOCKS 196   // ceil(50000/256)
#define BN_BLOCKS 391     // ceil(50000/128)
#define EDGE_BLOCKS 3125  // 800000/256
#define GEMM_BLOCKS 782   // ceil(50000/64)
#define NPART 8
#define PART_SZ 6250      // 50000/8
#define SUBS_F 256        // fill sub-blocks per partition (standalone)
#define FILLB_A 2048      // 8*256 fill blocks
#define DSL 50048         // per-slice degree counter stride

typedef __attribute__((ext_vector_type(8))) short short8;
typedef __attribute__((ext_vector_type(8))) unsigned short ushort8;
typedef __attribute__((ext_vector_type(4))) unsigned short ushortx4;
typedef __attribute__((ext_vector_type(4))) float f32x4;

// ---------------- runtime dtype adaptivity ----------------
// flags[0] = 1 if float inputs are fp32, 0 if bf16
// flags[1] = 1 if edge_index is int64, 0 if int32
// flags[2] = global CSR allocation cursor
static __device__ __forceinline__ float loadF(const void* p, int i, int f32) {
    if (f32) return ((const float*)p)[i];
    return __bfloat162float(((const __hip_bfloat16*)p)[i]);
}
static __device__ __forceinline__ float bfu2f(unsigned short u) {
    unsigned int t = ((unsigned int)u) << 16;
    float f;
    __builtin_memcpy(&f, &t, 4);
    return f;
}
static __device__ __forceinline__ short f2bf_s(float f) {
    union { __hip_bfloat16 b; short s; } cv;
    cv.b = __float2bfloat16(f);
    return cv.s;
}
static __device__ __forceinline__ unsigned short f2bf_u(float f) {
    union { __hip_bfloat16 b; unsigned short u; } cv;
    cv.b = __float2bfloat16(f);
    return cv.u;
}

// ---- weight prep: [block 0] dtype detect -> flags; [1..64] transpose weights
// (self-detected float dtype). Tiny (65 blocks) — runs before edge∥gemm1. ----
__global__ void k_wprep(const void* __restrict__ W1, const void* __restrict__ Wmu,
                        const void* __restrict__ Wls, const unsigned short* __restrict__ xs,
                        const void* __restrict__ ei, __hip_bfloat16* __restrict__ Wt1,
                        __hip_bfloat16* __restrict__ Wt2, int* __restrict__ flags) {
    int b = blockIdx.x;
    int t = threadIdx.x;
    if (b == 0) {
        __shared__ int cnt[2];
        if (t < 2) cnt[t] = 0;
        __syncthreads();
        unsigned short v = xs[2 * t];
        int e = (v >> 7) & 0xff;
        int sane = (e >= 112 && e <= 133) ? 1 : 0;
        if (v == 0 || v == 0x8000) sane = 1;
        atomicAdd(&cnt[0], sane);
        atomicAdd(&cnt[1], (((const int*)ei)[2 * t + 1] != 0) ? 1 : 0);
        __syncthreads();
        if (t == 0) {
            flags[0] = (cnt[0] < 128) ? 1 : 0;  // few sane bf16 patterns => fp32
            flags[1] = (cnt[1] < 8) ? 1 : 0;    // all-zero odd slots => int64
            flags[2] = 0;                       // CSR bump-allocation cursor
        }
    } else {
        // self-detect float dtype from W1 bit patterns (sigma~0.09 => sane bf16 exps)
        __shared__ int cnt;
        if (t == 0) cnt = 0;
        __syncthreads();
        unsigned short v = ((const unsigned short*)W1)[2 * t];
        int e = (v >> 7) & 0xff;
        atomicAdd(&cnt, (e >= 100 && e <= 133) ? 1 : 0);
        __syncthreads();
        int f32 = (cnt < 128) ? 1 : 0;
        int idx = (b - 1) * 256 + t;  // 16384 total
        int n = idx >> 7, k = idx & 127;
        Wt1[idx] = __float2bfloat16(loadF(W1, k * F + n, f32));
        float v2 = (n < L) ? loadF(Wmu, k * L + n, f32) : loadF(Wls, k * L + (n - L), f32);
        Wt2[idx] = __float2bfloat16(v2);
    }
}

// ---- MFMA GEMM body (operand-SWAPPED): out[node][n] via mfma(Wfrag, Xfrag).
// Writes UNSCALED result (isd applied per-source in aggregation) — removes the
// gemm->degree dependency so gemm1 can overlap edge processing.
// mode 0: conv1 — Xin dtype per flags[0]. mode 1: conv2 — bf16 h_pre with fused
// BN(scale,shift)+relu prologue (vectorized coefficient loads).
static __device__ __forceinline__ void gemm_body(int bid, const void* __restrict__ Xin,
        const __hip_bfloat16* __restrict__ Wt, const int* __restrict__ flags, int mode,
        const float* __restrict__ bnscale, const float* __restrict__ bnshift,
        unsigned short* __restrict__ outb) {
    int wave = threadIdx.x >> 6, lane = threadIdx.x & 63;
    int quad = lane >> 4, mr = lane & 15;
    int m0 = bid * 64 + wave * 16;
    int node = m0 + mr;
    int row = (node < N_NODES) ? node : N_NODES - 1;
    short8 a[4];
    if (mode == 1) {
        const unsigned short* xb = (const unsigned short*)Xin;
#pragma unroll
        for (int t = 0; t < 4; ++t) {
            int k0 = t * 32 + quad * 8;
            ushort8 raw = *(const ushort8*)(xb + row * F + k0);
            f32x4 s0 = *(const f32x4*)(bnscale + k0);
            f32x4 s1 = *(const f32x4*)(bnscale + k0 + 4);
            f32x4 h0 = *(const f32x4*)(bnshift + k0);
            f32x4 h1 = *(const f32x4*)(bnshift + k0 + 4);
            short8 av;
#pragma unroll
            for (int j = 0; j < 4; ++j)
                av[j] = f2bf_s(fmaxf(bfu2f(raw[j]) * s0[j] + h0[j], 0.f));
#pragma unroll
            for (int j = 0; j < 4; ++j)
                av[4 + j] = f2bf_s(fmaxf(bfu2f(raw[4 + j]) * s1[j] + h1[j], 0.f));
            a[t] = av;
        }
    } else if (flags[0]) {
        const float* xf = (const float*)Xin;
#pragma unroll
        for (int t = 0; t < 4; ++t) {
            int off = row * F + t * 32 + quad * 8;
            f32x4 v0 = *(const f32x4*)(xf + off);
            f32x4 v1 = *(const f32x4*)(xf + off + 4);
            short8 av;
#pragma unroll
            for (int j = 0; j < 4; ++j) av[j] = f2bf_s(v0[j]);
#pragma unroll
            for (int j = 0; j < 4; ++j) av[4 + j] = f2bf_s(v1[j]);
            a[t] = av;
        }
    } else {
        const short* xb = (const short*)Xin;
#pragma unroll
        for (int t = 0; t < 4; ++t)
            a[t] = *(const short8*)(xb + row * F + t * 32 + quad * 8);
    }
    f32x4 acc[8];
    const short* wb = (const short*)Wt;
#pragma unroll
    for (int nt = 0; nt < 8; ++nt) {
        const short* wp = wb + (nt * 16 + mr) * F + quad * 8;
        f32x4 c = {0.f, 0.f, 0.f, 0.f};
        c = __builtin_amdgcn_mfma_f32_16x16x32_bf16(*(const short8*)(wp), a[0], c, 0, 0, 0);
        c = __builtin_amdgcn_mfma_f32_16x16x32_bf16(*(const short8*)(wp + 32), a[1], c, 0, 0, 0);
        c = __builtin_amdgcn_mfma_f32_16x16x32_bf16(*(const short8*)(wp + 64), a[2], c, 0, 0, 0);
        c = __builtin_amdgcn_mfma_f32_16x16x32_bf16(*(const short8*)(wp + 96), a[3], c, 0, 0, 0);
        acc[nt] = c;
    }
    if (node < N_NODES) {
        unsigned short* op = outb + node * F;
#pragma unroll
        for (int nt = 0; nt < 8; ++nt) {
            ushortx4 r;
#pragma unroll
            for (int j = 0; j < 4; ++j) r[j] = f2bf_u(acc[nt][j]);
            *(ushortx4*)(op + nt * 16 + quad * 4) = r;
        }
    }
}

// ---- fused: [0..781] conv1 GEMM (unscaled; needs only Wt1+x) ||
// [782..3906] per-edge degree count + RANK capture into the REQUESTER-XCD
// slice degi8[blockIdx&7]: each counter line is touched by ONE XCD only ->
// no cross-XCD line migration (R12 measured ~18MB of migration write-backs).
// Rank is unique within (g,d); fill recovers g deterministically from e. ----
__global__ __launch_bounds__(256) void k_edge_gemm1(
        const void* __restrict__ X, const __hip_bfloat16* __restrict__ Wt1,
        const int* __restrict__ flags, const void* __restrict__ ei,
        int* __restrict__ degi8, int* __restrict__ src32, int* __restrict__ dst32,
        int* __restrict__ rank, unsigned short* __restrict__ outb) {
    if (blockIdx.x < GEMM_BLOCKS) {
        gemm_body(blockIdx.x, X, Wt1, flags, 0, nullptr, nullptr, outb);
    } else {
        // edge block: self-detect i64 from own window, then degree-count + rank
        int t = threadIdx.x;
        int e0 = (blockIdx.x - GEMM_BLOCKS) * 256 + t;  // < 800000 exactly
        int g = blockIdx.x & (NPART - 1);               // requester slice
        __shared__ int nz;
        if (t == 0) nz = 0;
        __syncthreads();
        int w = ((const int*)ei)[2 * e0 + 1];  // i64: high word (0); i32: random ids
        if (w != 0) atomicAdd(&nz, 1);
        __syncthreads();
        int d;
        if (nz < 8) {  // int64
            int s = (int)((const long long*)ei)[e0];
            d = (int)((const long long*)ei)[N_EDGES + e0];
            src32[e0] = s;
            dst32[e0] = d;
        } else {
            d = ((const int*)ei)[N_EDGES + e0];
        }
        rank[e0] = atomicAdd(&degi8[g * DSL + d], 1);  // slot within (g, node d)
    }
}

// ---- single-pass offsets: sum the 8 per-XCD degree slices, in-block LDS scan
// + ONE atomic block-base alloc. Writes total degi, offs, isd, and per-slice
// bases base8[g][i] = offs[i] + prefix_g (for the atomic-free fill). ----
__global__ void k_offs_alloc(const int* __restrict__ degi8, int* __restrict__ flags,
                             int* __restrict__ offs, float* __restrict__ isd,
                             int* __restrict__ degi, int* __restrict__ base8) {
    __shared__ int s[256];
    __shared__ int base;
    int t = threadIdx.x;
    int i = blockIdx.x * 256 + t;
    int c[NPART];
    int v = 0;
    if (i < N_NODES) {
#pragma unroll
        for (int g = 0; g < NPART; ++g) {
            c[g] = degi8[g * DSL + i];
            v += c[g];
        }
    }
    s[t] = v;
    __syncthreads();
    for (int o = 1; o < 256; o <<= 1) {
        int u = (t >= o) ? s[t - o] : 0;
        __syncthreads();
        s[t] += u;
        __syncthreads();
    }
    if (t == 255) base = atomicAdd(&flags[2], s[255]);
    __syncthreads();
    if (i < N_NODES) {
        int o0 = base + s[t] - v;  // exclusive within block + dynamic base
        offs[i] = o0;
        degi[i] = v;
        isd[i] = 1.0f / sqrtf((float)v + 1.0f);
        int run = o0;
#pragma unroll
        for (int g = 0; g < NPART; ++g) {
            base8[g * DSL + i] = run;
            run += c[g];
        }
    }
}

// ---- ATOMIC-FREE XCD-partitioned CSR fill (standalone):
// csr[base8[g][d] + rank[e]] = src[e], g recovered from e (edge e was handled
// by block e/256+GEMM_BLOCKS => g = (e>>8 + GEMM_BLOCKS)&7). Partition
// grp = blockIdx&7 == XCD -> csr segment exclusively owned, clean write-back.
__global__ __launch_bounds__(256) void k_fill(
        const int* __restrict__ ei32, const int* __restrict__ src32,
        const int* __restrict__ dst32, const int* __restrict__ rank,
        const int* __restrict__ flags, const int* __restrict__ base8,
        int* __restrict__ csr) {
    const int* sp;
    const int* dp;
    if (flags[1]) { sp = src32; dp = dst32; }
    else          { sp = ei32;  dp = ei32 + N_EDGES; }
    int grp = blockIdx.x & (NPART - 1);   // == XCD id (heuristic)
    int sub = blockIdx.x >> 3;            // 0..SUBS_F-1
    int lo = grp * PART_SZ, hi = lo + PART_SZ;
    int stride = SUBS_F * 256;
    for (int e = sub * 256 + threadIdx.x; e < N_EDGES; e += stride) {
        int d = dp[e];
        if (d >= lo && d < hi) {
            int g = ((e >> 8) + GEMM_BLOCKS) & (NPART - 1);
            csr[base8[g * DSL + d] + rank[e]] = sp[e];
        }
    }
}

__global__ __launch_bounds__(256) void k_gemm_bn(const void* __restrict__ Xin,
        const __hip_bfloat16* __restrict__ Wt, const int* __restrict__ flags,
        const float* __restrict__ bnscale, const float* __restrict__ bnshift,
        unsigned short* __restrict__ outb) {
    gemm_body(blockIdx.x, Xin, Wt, flags, 1, bnscale, bnshift, outb);
}

// ---- shared aggregation core: wave=node, 4 groups of 16 lanes, 4-deep unrolled
// gather. Values are UNSCALED; apply per-source isd[s] (and isd[node] for the
// self loop) during accumulation. Segment is [offs[node], offs[node]+deg). ----
static __device__ __forceinline__ void agg_accum(int node, int grp, int l16,
        const ushort8* __restrict__ vp, const int* __restrict__ csr,
        const int* __restrict__ offs, const int* __restrict__ degi,
        const float* __restrict__ isd, float acc[8]) {
#pragma unroll
    for (int j = 0; j < 8; ++j) acc[j] = 0.f;
    if (grp == 0) {
        float w = isd[node];
        ushort8 u = vp[node * 16 + l16];  // self loop
#pragma unroll
        for (int j = 0; j < 8; ++j) acc[j] = bfu2f(u[j]) * w;
    }
    int start = offs[node];
    int end = start + degi[node];
    int i = start + grp;
    for (; i + 12 < end; i += 16) {
        int s0 = csr[i], s1 = csr[i + 4], s2 = csr[i + 8], s3 = csr[i + 12];
        float w0 = isd[s0], w1 = isd[s1], w2 = isd[s2], w3 = isd[s3];
        ushort8 u0 = vp[s0 * 16 + l16];
        ushort8 u1 = vp[s1 * 16 + l16];
        ushort8 u2 = vp[s2 * 16 + l16];
        ushort8 u3 = vp[s3 * 16 + l16];
#pragma unroll
        for (int j = 0; j < 8; ++j)
            acc[j] += (bfu2f(u0[j]) * w0 + bfu2f(u1[j]) * w1) +
                      (bfu2f(u2[j]) * w2 + bfu2f(u3[j]) * w3);
    }
    for (; i + 4 < end; i += 8) {
        int s0 = csr[i], s1 = csr[i + 4];
        float w0 = isd[s0], w1 = isd[s1];
        ushort8 u0 = vp[s0 * 16 + l16];
        ushort8 u1 = vp[s1 * 16 + l16];
#pragma unroll
        for (int j = 0; j < 8; ++j) acc[j] += bfu2f(u0[j]) * w0 + bfu2f(u1[j]) * w1;
    }
    for (; i < end; i += 4) {
        int s0 = csr[i];
        float w0 = isd[s0];
        ushort8 u = vp[s0 * 16 + l16];
#pragma unroll
        for (int j = 0; j < 8; ++j) acc[j] += bfu2f(u[j]) * w0;
    }
#pragma unroll
    for (int j = 0; j < 8; ++j) {
        acc[j] += __shfl_xor(acc[j], 16);
        acc[j] += __shfl_xor(acc[j], 32);
    }
}

// ---- aggregate1: h_pre[d] = isd[d]*(A'[d]isd[d] + sum A'[s]isd[s]) + b1 ----
__global__ void k_agg1(const unsigned short* __restrict__ val, const int* __restrict__ csr,
                       const int* __restrict__ offs, const int* __restrict__ degi,
                       const float* __restrict__ isd, const void* __restrict__ b1,
                       const int* __restrict__ flags, unsigned short* __restrict__ out) {
    int node = blockIdx.x * 4 + (threadIdx.x >> 6);
    if (node >= N_NODES) return;
    int lane = threadIdx.x & 63;
    int grp = lane >> 4, l16 = lane & 15;
    float acc[8];
    agg_accum(node, grp, l16, (const ushort8*)val, csr, offs, degi, isd, acc);
    if (grp == 0) {
        float sd = isd[node];
        int c0 = l16 * 8, f32 = flags[0];
        ushort8 r;
#pragma unroll
        for (int j = 0; j < 8; ++j) r[j] = f2bf_u(acc[j] * sd + loadF(b1, c0 + j, f32));
        ((ushort8*)out)[node * 16 + l16] = r;
    }
}

// ---- BN stats phase 1: per-block column sums / sum-of-squares (no atomics) ----
__global__ void k_bnstats(const unsigned short* __restrict__ h, float* __restrict__ partial) {
    __shared__ float ls[256][8];
    __shared__ float lq[256][8];
    int t = threadIdx.x;
    int o = t & 15, rg = t >> 4;
    int row0 = blockIdx.x * 128 + rg;
    float s[8] = {0.f}, q[8] = {0.f};
#pragma unroll
    for (int i = 0; i < 8; ++i) {
        int row = row0 + i * 16;
        if (row < N_NODES) {
            ushort8 u = *(const ushort8*)(h + row * F + o * 8);
#pragma unroll
            for (int j = 0; j < 8; ++j) {
                float v = bfu2f(u[j]);
                s[j] += v;
                q[j] += v * v;
            }
        }
    }
#pragma unroll
    for (int j = 0; j < 8; ++j) { ls[t][j] = s[j]; lq[t][j] = q[j]; }
    __syncthreads();
    if (t < 128) {
        int c = t, oo = c >> 3, jj = c & 7;
        float ts = 0.f, tq = 0.f;
#pragma unroll
        for (int rgi = 0; rgi < 16; ++rgi) {
            ts += ls[rgi * 16 + oo][jj];
            tq += lq[rgi * 16 + oo][jj];
        }
        partial[blockIdx.x * 256 + c] = ts;
        partial[blockIdx.x * 256 + 128 + c] = tq;
    }
}

// ---- fused BN reduce + coefficient prep: block c -> scale[c], shift[c] ----
__global__ void k_bnredprep(const float* __restrict__ partial, const void* __restrict__ gamma,
                            const void* __restrict__ beta, const int* __restrict__ flags,
                            float* __restrict__ scale, float* __restrict__ shift) {
    int c = blockIdx.x;  // 0..127
    float s = 0.f, q = 0.f;
    for (int b = threadIdx.x; b < BN_BLOCKS; b += 256) {
        s += partial[b * 256 + c];
        q += partial[b * 256 + 128 + c];
    }
#pragma unroll
    for (int o = 32; o; o >>= 1) {
        s += __shfl_down(s, o);
        q += __shfl_down(q, o);
    }
    __shared__ float ws[4], wq[4];
    if ((threadIdx.x & 63) == 0) {
        ws[threadIdx.x >> 6] = s;
        wq[threadIdx.x >> 6] = q;
    }
    __syncthreads();
    if (threadIdx.x == 0) {
        float S = ws[0] + ws[1] + ws[2] + ws[3];
        float Q = wq[0] + wq[1] + wq[2] + wq[3];
        const float invN = 1.0f / (float)N_NODES;
        float m = S * invN;
        float var = Q * invN - m * m;
        int f32 = flags[0];
        float sc = loadF(gamma, c, f32) * rsqrtf(var + BN_EPS);
        scale[c] = sc;
        shift[c] = loadF(beta, c, f32) - m * sc;
    }
}

// ---- aggregate2 + epilogue: write mu[N,64] ++ log_std[N,64] in output dtype ----
__global__ void k_agg2(const unsigned short* __restrict__ val, const int* __restrict__ csr,
                       const int* __restrict__ offs, const int* __restrict__ degi,
                       const float* __restrict__ isd, const void* __restrict__ bmu,
                       const void* __restrict__ bls, const int* __restrict__ flags,
                       void* __restrict__ out) {
    int node = blockIdx.x * 4 + (threadIdx.x >> 6);
    if (node >= N_NODES) return;
    int lane = threadIdx.x & 63;
    int grp = lane >> 4, l16 = lane & 15;
    float acc[8];
    agg_accum(node, grp, l16, (const ushort8*)val, csr, offs, degi, isd, acc);
    if (grp == 0) {
        float sd = isd[node];
        int c0 = l16 * 8, f32 = flags[0];
        int hsel = (c0 >= L) ? 1 : 0;
        int cc = c0 - hsel * L;
        const void* bp = hsel ? bls : bmu;
        float o8[8];
#pragma unroll
        for (int j = 0; j < 8; ++j) o8[j] = acc[j] * sd + loadF(bp, cc + j, f32);
        long base_o = (long)hsel * (N_NODES * 64) + (long)node * 64 + cc;
        if (f32) {
            f32x4 r0 = {o8[0], o8[1], o8[2], o8[3]};
            f32x4 r1 = {o8[4], o8[5], o8[6], o8[7]};
            __builtin_nontemporal_store(r0, (f32x4*)((float*)out + base_o));
            __builtin_nontemporal_store(r1, (f32x4*)((float*)out + base_o + 4));
        } else {
            ushort8 r;
#pragma unroll
            for (int j = 0; j < 8; ++j) r[j] = f2bf_u(o8[j]);
            __builtin_nontemporal_store(r, (ushort8*)((__hip_bfloat16*)out + base_o));
        }
    }
}

extern "C" void kernel_launch(void* const* d_in, const int* in_sizes, int n_in,
                              void* d_out, int out_size, void* d_ws, size_t ws_size,
                              hipStream_t stream) {
    const void* x     = d_in[0];
    const void* ei    = d_in[1];
    const void* W1    = d_in[2];
    const void* b1    = d_in[3];
    const void* gamma = d_in[4];
    const void* beta  = d_in[5];
    const void* Wmu   = d_in[6];
    const void* bmu   = d_in[7];
    const void* Wls   = d_in[8];
    const void* bls   = d_in[9];

    int*   degi8 = (int*)d_ws;                     // [8*50048] per-XCD degree slices
    int*   base8 = degi8 + NPART * DSL;            // [8*50048] per-slice csr bases
    int*   degi  = base8 + NPART * DSL;            // [50048] total degrees
    int*   offs  = degi + 50048;                   // [50048] exclusive starts
    float* isd   = (float*)(offs + 50048);         // [50048]
    float* stats = isd + 50048;                    // scale[128] shift[128] (+pad)
    int*   flags = (int*)(stats + 512);            // [16] (flags[2]=alloc cursor)
    int*   csr   = flags + 16;                     // [800000]
    int*   src32 = csr + 800000;                   // [800000] (int64 case only)
    int*   dst32 = src32 + 800000;                 // [800000] (int64 case only)
    int*   rank  = dst32 + 800000;                 // [800000] per-edge slot in (g,node)
    __hip_bfloat16* Wt1 = (__hip_bfloat16*)(rank + 800000);  // [16384]
    __hip_bfloat16* Wt2 = Wt1 + 16384;                       // [16384]
    unsigned short* Abf = (unsigned short*)(Wt2 + 16384);    // [N*128] bf16 A'
    unsigned short* Hpre = Abf + N_NODES * F;                // [N*128] bf16 h_pre
    float* partial = (float*)(Hpre + N_NODES * F);           // [BN_BLOCKS*256]

    const int NT = 256;
    const int AGG_BLOCKS = (N_NODES + 3) / 4;

    // zero per-XCD degree slices (1.6MB, async, graph-capturable)
    hipMemsetAsync(degi8, 0, (size_t)NPART * DSL * sizeof(int), stream);
    // flags + weight transpose (tiny)
    k_wprep<<<65, NT, 0, stream>>>(W1, Wmu, Wls, (const unsigned short*)x, ei,
                                   Wt1, Wt2, flags);
    // conv1 GEMM (unscaled, needs only Wt1) || edge degree/rank/convert — overlap
    k_edge_gemm1<<<GEMM_BLOCKS + EDGE_BLOCKS, NT, 0, stream>>>(
        x, Wt1, flags, ei, degi8, src32, dst32, rank, Abf);
    // offsets: sum 8 slices, scan, alloc; emit degi/offs/isd/base8
    k_offs_alloc<<<SCAN_BLOCKS, NT, 0, stream>>>(degi8, flags, offs, isd, degi, base8);
    // atomic-free XCD-partitioned CSR fill
    k_fill<<<FILLB_A, NT, 0, stream>>>((const int*)ei, src32, dst32, rank,
                                       flags, base8, csr);
    // aggregate conv1 + per-source isd + bias
    k_agg1<<<AGG_BLOCKS, NT, 0, stream>>>(Abf, csr, offs, degi, isd, b1, flags, Hpre);
    // batchnorm stats (2-phase, no atomics) + fused reduce/prep
    k_bnstats<<<BN_BLOCKS, NT, 0, stream>>>(Hpre, partial);
    k_bnredprep<<<128, NT, 0, stream>>>(partial, gamma, beta, flags, stats, stats + 128);
    // conv2: A'2 = relu(bn(h_pre)) @ [Wmu|Wls] -> bf16 unscaled (reuses Abf)
    k_gemm_bn<<<GEMM_BLOCKS, NT, 0, stream>>>(Hpre, Wt2, flags, stats, stats + 128, Abf);
    // aggregate conv2 + epilogue
    k_agg2<<<AGG_BLOCKS, NT, 0, stream>>>(Abf, csr, offs, degi, isd, bmu, bls, flags, d_out);
}

// Round 14
// 271.663 us; speedup vs baseline: 1.0110x; 1.0110x over previous
//
#include <hip/hip_runtime.h>
#include <hip/hip_bf16.h>

#define N_NODES 50000
#define N_EDGES 800000
#define F 128
#define L 64
#define BN_EPS 1e-5f
#define SCAN_BLOCKS 196   // ceil(50000/256)
#define BN_BLOCKS 391     // ceil(50000/128)
#define EDGE_BLOCKS2 1563 // ceil(800000/512), 2 edges/thread
#define GEMM_BLOCKS 782   // ceil(50000/64)
#define NPART 8
#define PART_SZ 6250      // 50000/8
#define SUBS_F 256        // fill sub-blocks per partition
#define FILLB_A 2048      // 8*256 fill blocks

typedef __attribute__((ext_vector_type(8))) short short8;
typedef __attribute__((ext_vector_type(8))) unsigned short ushort8;
typedef __attribute__((ext_vector_type(4))) unsigned short ushortx4;
typedef __attribute__((ext_vector_type(4))) float f32x4;

// ---------------- runtime dtype adaptivity ----------------
// flags[0] = 1 if float inputs are fp32, 0 if bf16
// flags[1] = 1 if edge_index is int64, 0 if int32
// flags[2] = global CSR allocation cursor
static __device__ __forceinline__ float loadF(const void* p, int i, int f32) {
    if (f32) return ((const float*)p)[i];
    return __bfloat162float(((const __hip_bfloat16*)p)[i]);
}
static __device__ __forceinline__ float bfu2f(unsigned short u) {
    unsigned int t = ((unsigned int)u) << 16;
    float f;
    __builtin_memcpy(&f, &t, 4);
    return f;
}
static __device__ __forceinline__ short f2bf_s(float f) {
    union { __hip_bfloat16 b; short s; } cv;
    cv.b = __float2bfloat16(f);
    return cv.s;
}
static __device__ __forceinline__ unsigned short f2bf_u(float f) {
    union { __hip_bfloat16 b; unsigned short u; } cv;
    cv.b = __float2bfloat16(f);
    return cv.u;
}

// ---- weight prep: [block 0] dtype detect -> flags; [1..64] transpose weights
// (self-detected float dtype); [65..260] zero degi (replaces hipMemsetAsync).
__global__ void k_wprep(const void* __restrict__ W1, const void* __restrict__ Wmu,
                        const void* __restrict__ Wls, const unsigned short* __restrict__ xs,
                        const void* __restrict__ ei, __hip_bfloat16* __restrict__ Wt1,
                        __hip_bfloat16* __restrict__ Wt2, int* __restrict__ flags,
                        int* __restrict__ degi) {
    int b = blockIdx.x;
    int t = threadIdx.x;
    if (b == 0) {
        __shared__ int cnt[2];
        if (t < 2) cnt[t] = 0;
        __syncthreads();
        unsigned short v = xs[2 * t];
        int e = (v >> 7) & 0xff;
        int sane = (e >= 112 && e <= 133) ? 1 : 0;
        if (v == 0 || v == 0x8000) sane = 1;
        atomicAdd(&cnt[0], sane);
        atomicAdd(&cnt[1], (((const int*)ei)[2 * t + 1] != 0) ? 1 : 0);
        __syncthreads();
        if (t == 0) {
            flags[0] = (cnt[0] < 128) ? 1 : 0;  // few sane bf16 patterns => fp32
            flags[1] = (cnt[1] < 8) ? 1 : 0;    // all-zero odd slots => int64
            flags[2] = 0;                       // CSR bump-allocation cursor
        }
    } else if (b <= 64) {
        // self-detect float dtype from W1 bit patterns (sigma~0.09 => sane bf16 exps)
        __shared__ int cnt;
        if (t == 0) cnt = 0;
        __syncthreads();
        unsigned short v = ((const unsigned short*)W1)[2 * t];
        int e = (v >> 7) & 0xff;
        atomicAdd(&cnt, (e >= 100 && e <= 133) ? 1 : 0);
        __syncthreads();
        int f32 = (cnt < 128) ? 1 : 0;
        int idx = (b - 1) * 256 + t;  // 16384 total
        int n = idx >> 7, k = idx & 127;
        Wt1[idx] = __float2bfloat16(loadF(W1, k * F + n, f32));
        float v2 = (n < L) ? loadF(Wmu, k * L + n, f32) : loadF(Wls, k * L + (n - L), f32);
        Wt2[idx] = __float2bfloat16(v2);
    } else {
        int i = (b - 65) * 256 + t;
        if (i < 50048) degi[i] = 0;
    }
}

// ---- MFMA GEMM body (operand-SWAPPED): out[node][n] via mfma(Wfrag, Xfrag).
// Writes UNSCALED result (isd applied per-source in aggregation) — removes the
// gemm->degree dependency so gemm1 can overlap edge processing.
// mode 0: conv1 — Xin dtype per flags[0]. mode 1: conv2 — bf16 h_pre with fused
// BN(scale,shift)+relu prologue (vectorized coefficient loads).
static __device__ __forceinline__ void gemm_body(int bid, const void* __restrict__ Xin,
        const __hip_bfloat16* __restrict__ Wt, const int* __restrict__ flags, int mode,
        const float* __restrict__ bnscale, const float* __restrict__ bnshift,
        unsigned short* __restrict__ outb) {
    int wave = threadIdx.x >> 6, lane = threadIdx.x & 63;
    int quad = lane >> 4, mr = lane & 15;
    int m0 = bid * 64 + wave * 16;
    int node = m0 + mr;
    int row = (node < N_NODES) ? node : N_NODES - 1;
    short8 a[4];
    if (mode == 1) {
        const unsigned short* xb = (const unsigned short*)Xin;
#pragma unroll
        for (int t = 0; t < 4; ++t) {
            int k0 = t * 32 + quad * 8;
            ushort8 raw = *(const ushort8*)(xb + row * F + k0);
            f32x4 s0 = *(const f32x4*)(bnscale + k0);
            f32x4 s1 = *(const f32x4*)(bnscale + k0 + 4);
            f32x4 h0 = *(const f32x4*)(bnshift + k0);
            f32x4 h1 = *(const f32x4*)(bnshift + k0 + 4);
            short8 av;
#pragma unroll
            for (int j = 0; j < 4; ++j)
                av[j] = f2bf_s(fmaxf(bfu2f(raw[j]) * s0[j] + h0[j], 0.f));
#pragma unroll
            for (int j = 0; j < 4; ++j)
                av[4 + j] = f2bf_s(fmaxf(bfu2f(raw[4 + j]) * s1[j] + h1[j], 0.f));
            a[t] = av;
        }
    } else if (flags[0]) {
        const float* xf = (const float*)Xin;
#pragma unroll
        for (int t = 0; t < 4; ++t) {
            int off = row * F + t * 32 + quad * 8;
            f32x4 v0 = *(const f32x4*)(xf + off);
            f32x4 v1 = *(const f32x4*)(xf + off + 4);
            short8 av;
#pragma unroll
            for (int j = 0; j < 4; ++j) av[j] = f2bf_s(v0[j]);
#pragma unroll
            for (int j = 0; j < 4; ++j) av[4 + j] = f2bf_s(v1[j]);
            a[t] = av;
        }
    } else {
        const short* xb = (const short*)Xin;
#pragma unroll
        for (int t = 0; t < 4; ++t)
            a[t] = *(const short8*)(xb + row * F + t * 32 + quad * 8);
    }
    f32x4 acc[8];
    const short* wb = (const short*)Wt;
#pragma unroll
    for (int nt = 0; nt < 8; ++nt) {
        const short* wp = wb + (nt * 16 + mr) * F + quad * 8;
        f32x4 c = {0.f, 0.f, 0.f, 0.f};
        c = __builtin_amdgcn_mfma_f32_16x16x32_bf16(*(const short8*)(wp), a[0], c, 0, 0, 0);
        c = __builtin_amdgcn_mfma_f32_16x16x32_bf16(*(const short8*)(wp + 32), a[1], c, 0, 0, 0);
        c = __builtin_amdgcn_mfma_f32_16x16x32_bf16(*(const short8*)(wp + 64), a[2], c, 0, 0, 0);
        c = __builtin_amdgcn_mfma_f32_16x16x32_bf16(*(const short8*)(wp + 96), a[3], c, 0, 0, 0);
        acc[nt] = c;
    }
    if (node < N_NODES) {
        unsigned short* op = outb + node * F;
#pragma unroll
        for (int nt = 0; nt < 8; ++nt) {
            ushortx4 r;
#pragma unroll
            for (int j = 0; j < 4; ++j) r[j] = f2bf_u(acc[nt][j]);
            *(ushortx4*)(op + nt * 16 + quad * 4) = r;
        }
    }
}

// ---- fused: [0..781] conv1 GEMM (unscaled; needs only Wt1+x) ||
// [782..2344] edge processing, 2 edges/thread: degree count + RANK capture,
// emitting u16 streams (all ids < 2^16, rank < maxdeg ~45). The degree
// atomic's return value IS the edge's unique slot => fill needs NO atomics.
// degi must be pre-zeroed (done by k_wprep). ----
__global__ __launch_bounds__(256) void k_edge_gemm1(
        const void* __restrict__ X, const __hip_bfloat16* __restrict__ Wt1,
        const int* __restrict__ flags, const void* __restrict__ ei,
        int* __restrict__ degi, unsigned short* __restrict__ src16,
        unsigned short* __restrict__ dst16, unsigned short* __restrict__ rank16,
        unsigned short* __restrict__ outb) {
    if (blockIdx.x < GEMM_BLOCKS) {
        gemm_body(blockIdx.x, X, Wt1, flags, 0, nullptr, nullptr, outb);
    } else {
        // edge block: self-detect i64 from own window, then 2 edges/thread
        int t = threadIdx.x;
        int ebase = (blockIdx.x - GEMM_BLOCKS) * 512;
        __shared__ int nz;
        if (t == 0) nz = 0;
        __syncthreads();
        int e0 = ebase + t;
        if (e0 < N_EDGES) {
            int w = ((const int*)ei)[2 * e0 + 1];  // i64 high word vs i32 random id
            if (w != 0) atomicAdd(&nz, 1);
        }
        __syncthreads();
        int i64 = (nz < 8) ? 1 : 0;
#pragma unroll
        for (int k = 0; k < 2; ++k) {
            int e = ebase + k * 256 + t;
            if (e < N_EDGES) {
                int s, d;
                if (i64) {
                    s = (int)((const long long*)ei)[e];
                    d = (int)((const long long*)ei)[N_EDGES + e];
                } else {
                    s = ((const int*)ei)[e];
                    d = ((const int*)ei)[N_EDGES + e];
                }
                src16[e] = (unsigned short)s;
                dst16[e] = (unsigned short)d;
                rank16[e] = (unsigned short)atomicAdd(&degi[d], 1);
            }
        }
    }
}

// ---- single-pass offsets: in-block LDS scan + ONE atomic block-base alloc.
// Segment ORDER in csr is irrelevant (aggs use [offs, offs+deg)). ----
__global__ void k_offs_alloc(const int* __restrict__ degi, int* __restrict__ flags,
                             int* __restrict__ offs, float* __restrict__ isd) {
    __shared__ int s[256];
    __shared__ int base;
    int t = threadIdx.x;
    int i = blockIdx.x * 256 + t;
    int v = (i < N_NODES) ? degi[i] : 0;
    s[t] = v;
    __syncthreads();
    for (int o = 1; o < 256; o <<= 1) {
        int u = (t >= o) ? s[t - o] : 0;
        __syncthreads();
        s[t] += u;
        __syncthreads();
    }
    if (t == 255) base = atomicAdd(&flags[2], s[255]);
    __syncthreads();
    if (i < N_NODES) {
        offs[i] = base + s[t] - v;  // exclusive within block + dynamic base
        isd[i] = 1.0f / sqrtf((float)v + 1.0f);
    }
}

// ---- ATOMIC-FREE XCD-partitioned CSR fill: csr16[offs[d]+rank16[e]] = src16[e]
// (positions provably unique). grp = blockIdx&7 == XCD (round-robin) -> each
// XCD's L2 exclusively owns its offs slice (hot) and csr segment. u16 streams
// halve all fill traffic vs int32. ----
__global__ __launch_bounds__(256) void k_fill(
        const unsigned short* __restrict__ src16, const unsigned short* __restrict__ dst16,
        const unsigned short* __restrict__ rank16, const int* __restrict__ offs,
        unsigned short* __restrict__ csr16) {
    int grp = blockIdx.x & (NPART - 1);   // == XCD id (heuristic)
    int sub = blockIdx.x >> 3;            // 0..SUBS_F-1
    int lo = grp * PART_SZ, hi = lo + PART_SZ;
    int stride = SUBS_F * 256;
    for (int e = sub * 256 + threadIdx.x; e < N_EDGES; e += stride) {
        int d = dst16[e];
        if (d >= lo && d < hi) csr16[offs[d] + rank16[e]] = src16[e];
    }
}

__global__ __launch_bounds__(256) void k_gemm_bn(const void* __restrict__ Xin,
        const __hip_bfloat16* __restrict__ Wt, const int* __restrict__ flags,
        const float* __restrict__ bnscale, const float* __restrict__ bnshift,
        unsigned short* __restrict__ outb) {
    gemm_body(blockIdx.x, Xin, Wt, flags, 1, bnscale, bnshift, outb);
}

// ---- shared aggregation core: wave=node, 4 groups of 16 lanes, 4-deep unrolled
// gather. Values are UNSCALED; apply per-source isd[s] (and isd[node] for the
// self loop) during accumulation. Segment is [offs[node], offs[node]+deg). ----
static __device__ __forceinline__ void agg_accum(int node, int grp, int l16,
        const ushort8* __restrict__ vp, const unsigned short* __restrict__ csr,
        const int* __restrict__ offs, const int* __restrict__ degi,
        const float* __restrict__ isd, float acc[8]) {
#pragma unroll
    for (int j = 0; j < 8; ++j) acc[j] = 0.f;
    if (grp == 0) {
        float w = isd[node];
        ushort8 u = vp[node * 16 + l16];  // self loop
#pragma unroll
        for (int j = 0; j < 8; ++j) acc[j] = bfu2f(u[j]) * w;
    }
    int start = offs[node];
    int end = start + degi[node];
    int i = start + grp;
    for (; i + 12 < end; i += 16) {
        int s0 = csr[i], s1 = csr[i + 4], s2 = csr[i + 8], s3 = csr[i + 12];
        float w0 = isd[s0], w1 = isd[s1], w2 = isd[s2], w3 = isd[s3];
        ushort8 u0 = vp[s0 * 16 + l16];
        ushort8 u1 = vp[s1 * 16 + l16];
        ushort8 u2 = vp[s2 * 16 + l16];
        ushort8 u3 = vp[s3 * 16 + l16];
#pragma unroll
        for (int j = 0; j < 8; ++j)
            acc[j] += (bfu2f(u0[j]) * w0 + bfu2f(u1[j]) * w1) +
                      (bfu2f(u2[j]) * w2 + bfu2f(u3[j]) * w3);
    }
    for (; i + 4 < end; i += 8) {
        int s0 = csr[i], s1 = csr[i + 4];
        float w0 = isd[s0], w1 = isd[s1];
        ushort8 u0 = vp[s0 * 16 + l16];
        ushort8 u1 = vp[s1 * 16 + l16];
#pragma unroll
        for (int j = 0; j < 8; ++j) acc[j] += bfu2f(u0[j]) * w0 + bfu2f(u1[j]) * w1;
    }
    for (; i < end; i += 4) {
        int s0 = csr[i];
        float w0 = isd[s0];
        ushort8 u = vp[s0 * 16 + l16];
#pragma unroll
        for (int j = 0; j < 8; ++j) acc[j] += bfu2f(u[j]) * w0;
    }
#pragma unroll
    for (int j = 0; j < 8; ++j) {
        acc[j] += __shfl_xor(acc[j], 16);
        acc[j] += __shfl_xor(acc[j], 32);
    }
}

// ---- aggregate1: h_pre[d] = isd[d]*(A'[d]isd[d] + sum A'[s]isd[s]) + b1 ----
__global__ void k_agg1(const unsigned short* __restrict__ val,
                       const unsigned short* __restrict__ csr,
                       const int* __restrict__ offs, const int* __restrict__ degi,
                       const float* __restrict__ isd, const void* __restrict__ b1,
                       const int* __restrict__ flags, unsigned short* __restrict__ out) {
    int node = blockIdx.x * 4 + (threadIdx.x >> 6);
    if (node >= N_NODES) return;
    int lane = threadIdx.x & 63;
    int grp = lane >> 4, l16 = lane & 15;
    float acc[8];
    agg_accum(node, grp, l16, (const ushort8*)val, csr, offs, degi, isd, acc);
    if (grp == 0) {
        float sd = isd[node];
        int c0 = l16 * 8, f32 = flags[0];
        ushort8 r;
#pragma unroll
        for (int j = 0; j < 8; ++j) r[j] = f2bf_u(acc[j] * sd + loadF(b1, c0 + j, f32));
        ((ushort8*)out)[node * 16 + l16] = r;
    }
}

// ---- BN stats phase 1: per-block column sums / sum-of-squares (no atomics) ----
__global__ void k_bnstats(const unsigned short* __restrict__ h, float* __restrict__ partial) {
    __shared__ float ls[256][8];
    __shared__ float lq[256][8];
    int t = threadIdx.x;
    int o = t & 15, rg = t >> 4;
    int row0 = blockIdx.x * 128 + rg;
    float s[8] = {0.f}, q[8] = {0.f};
#pragma unroll
    for (int i = 0; i < 8; ++i) {
        int row = row0 + i * 16;
        if (row < N_NODES) {
            ushort8 u = *(const ushort8*)(h + row * F + o * 8);
#pragma unroll
            for (int j = 0; j < 8; ++j) {
                float v = bfu2f(u[j]);
                s[j] += v;
                q[j] += v * v;
            }
        }
    }
#pragma unroll
    for (int j = 0; j < 8; ++j) { ls[t][j] = s[j]; lq[t][j] = q[j]; }
    __syncthreads();
    if (t < 128) {
        int c = t, oo = c >> 3, jj = c & 7;
        float ts = 0.f, tq = 0.f;
#pragma unroll
        for (int rgi = 0; rgi < 16; ++rgi) {
            ts += ls[rgi * 16 + oo][jj];
            tq += lq[rgi * 16 + oo][jj];
        }
        partial[blockIdx.x * 256 + c] = ts;
        partial[blockIdx.x * 256 + 128 + c] = tq;
    }
}

// ---- fused BN reduce + coefficient prep: block c -> scale[c], shift[c] ----
__global__ void k_bnredprep(const float* __restrict__ partial, const void* __restrict__ gamma,
                            const void* __restrict__ beta, const int* __restrict__ flags,
                            float* __restrict__ scale, float* __restrict__ shift) {
    int c = blockIdx.x;  // 0..127
    float s = 0.f, q = 0.f;
    for (int b = threadIdx.x; b < BN_BLOCKS; b += 256) {
        s += partial[b * 256 + c];
        q += partial[b * 256 + 128 + c];
    }
#pragma unroll
    for (int o = 32; o; o >>= 1) {
        s += __shfl_down(s, o);
        q += __shfl_down(q, o);
    }
    __shared__ float ws[4], wq[4];
    if ((threadIdx.x & 63) == 0) {
        ws[threadIdx.x >> 6] = s;
        wq[threadIdx.x >> 6] = q;
    }
    __syncthreads();
    if (threadIdx.x == 0) {
        float S = ws[0] + ws[1] + ws[2] + ws[3];
        float Q = wq[0] + wq[1] + wq[2] + wq[3];
        const float invN = 1.0f / (float)N_NODES;
        float m = S * invN;
        float var = Q * invN - m * m;
        int f32 = flags[0];
        float sc = loadF(gamma, c, f32) * rsqrtf(var + BN_EPS);
        scale[c] = sc;
        shift[c] = loadF(beta, c, f32) - m * sc;
    }
}

// ---- aggregate2 + epilogue: write mu[N,64] ++ log_std[N,64] in output dtype ----
__global__ void k_agg2(const unsigned short* __restrict__ val,
                       const unsigned short* __restrict__ csr,
                       const int* __restrict__ offs, const int* __restrict__ degi,
                       const float* __restrict__ isd, const void* __restrict__ bmu,
                       const void* __restrict__ bls, const int* __restrict__ flags,
                       void* __restrict__ out) {
    int node = blockIdx.x * 4 + (threadIdx.x >> 6);
    if (node >= N_NODES) return;
    int lane = threadIdx.x & 63;
    int grp = lane >> 4, l16 = lane & 15;
    float acc[8];
    agg_accum(node, grp, l16, (const ushort8*)val, csr, offs, degi, isd, acc);
    if (grp == 0) {
        float sd = isd[node];
        int c0 = l16 * 8, f32 = flags[0];
        int hsel = (c0 >= L) ? 1 : 0;
        int cc = c0 - hsel * L;
        const void* bp = hsel ? bls : bmu;
        float o8[8];
#pragma unroll
        for (int j = 0; j < 8; ++j) o8[j] = acc[j] * sd + loadF(bp, cc + j, f32);
        long base_o = (long)hsel * (N_NODES * 64) + (long)node * 64 + cc;
        if (f32) {
            f32x4 r0 = {o8[0], o8[1], o8[2], o8[3]};
            f32x4 r1 = {o8[4], o8[5], o8[6], o8[7]};
            __builtin_nontemporal_store(r0, (f32x4*)((float*)out + base_o));
            __builtin_nontemporal_store(r1, (f32x4*)((float*)out + base_o + 4));
        } else {
            ushort8 r;
#pragma unroll
            for (int j = 0; j < 8; ++j) r[j] = f2bf_u(o8[j]);
            __builtin_nontemporal_store(r, (ushort8*)((__hip_bfloat16*)out + base_o));
        }
    }
}

extern "C" void kernel_launch(void* const* d_in, const int* in_sizes, int n_in,
                              void* d_out, int out_size, void* d_ws, size_t ws_size,
                              hipStream_t stream) {
    const void* x     = d_in[0];
    const void* ei    = d_in[1];
    const void* W1    = d_in[2];
    const void* b1    = d_in[3];
    const void* gamma = d_in[4];
    const void* beta  = d_in[5];
    const void* Wmu   = d_in[6];
    const void* bmu   = d_in[7];
    const void* Wls   = d_in[8];
    const void* bls   = d_in[9];

    int*   degi  = (int*)d_ws;                     // [50048] degrees
    int*   offs  = degi + 50048;                   // [50048] exclusive starts
    float* isd   = (float*)(offs + 50048);         // [50048]
    float* stats = isd + 50048;                    // scale[128] shift[128] (+pad)
    int*   flags = (int*)(stats + 512);            // [16] (flags[2]=alloc cursor)
    unsigned short* csr16  = (unsigned short*)(flags + 16);  // [800000] u16
    unsigned short* src16  = csr16 + 800000;                 // [800000] u16
    unsigned short* dst16  = src16 + 800000;                 // [800000] u16
    unsigned short* rank16 = dst16 + 800000;                 // [800000] u16
    __hip_bfloat16* Wt1 = (__hip_bfloat16*)(rank16 + 800000);// [16384]
    __hip_bfloat16* Wt2 = Wt1 + 16384;                       // [16384]
    unsigned short* Abf = (unsigned short*)(Wt2 + 16384);    // [N*128] bf16 A'
    unsigned short* Hpre = Abf + N_NODES * F;                // [N*128] bf16 h_pre
    float* partial = (float*)(Hpre + N_NODES * F);           // [BN_BLOCKS*256]

    const int NT = 256;
    const int AGG_BLOCKS = (N_NODES + 3) / 4;

    // flags + weight transpose + degi zero (one kernel; replaces memset)
    k_wprep<<<65 + SCAN_BLOCKS, NT, 0, stream>>>(W1, Wmu, Wls, (const unsigned short*)x,
                                                 ei, Wt1, Wt2, flags, degi);
    // conv1 GEMM (unscaled, needs only Wt1) || edge degree/rank/u16-convert
    k_edge_gemm1<<<GEMM_BLOCKS + EDGE_BLOCKS2, NT, 0, stream>>>(
        x, Wt1, flags, ei, degi, src16, dst16, rank16, Abf);
    // single-pass offsets via atomic block-base allocation
    k_offs_alloc<<<SCAN_BLOCKS, NT, 0, stream>>>(degi, flags, offs, isd);
    // atomic-free XCD-partitioned CSR fill (u16 streams)
    k_fill<<<FILLB_A, NT, 0, stream>>>(src16, dst16, rank16, offs, csr16);
    // aggregate conv1 + per-source isd + bias
    k_agg1<<<AGG_BLOCKS, NT, 0, stream>>>(Abf, csr16, offs, degi, isd, b1, flags, Hpre);
    // batchnorm stats (2-phase, no atomics) + fused reduce/prep
    k_bnstats<<<BN_BLOCKS, NT, 0, stream>>>(Hpre, partial);
    k_bnredprep<<<128, NT, 0, stream>>>(partial, gamma, beta, flags, stats, stats + 128);
    // conv2: A'2 = relu(bn(h_pre)) @ [Wmu|Wls] -> bf16 unscaled (reuses Abf)
    k_gemm_bn<<<GEMM_BLOCKS, NT, 0, stream>>>(Hpre, Wt2, flags, stats, stats + 128, Abf);
    // aggregate conv2 + epilogue
    k_agg2<<<AGG_BLOCKS, NT, 0, stream>>>(Abf, csr16, offs, degi, isd, bmu, bls, flags, d_out);
}

// Round 15
// 268.845 us; speedup vs baseline: 1.0216x; 1.0105x over previous
//
#include <hip/hip_runtime.h>
#include <hip/hip_bf16.h>

#define N_NODES 50000
#define N_EDGES 800000
#define F 128
#define L 64
#define BN_EPS 1e-5f
#define SCAN_BLOCKS 196   // ceil(50000/256)
#define BN_BLOCKS 391     // ceil(50000/128)
#define EDGE_BLOCKS2 1563 // ceil(800000/512), 2 edges/thread
#define GEMM_BLOCKS 782   // ceil(50000/64)
#define NPART 8
#define PART_SZ 6250      // 50000/8
#define SUBS_F 256        // fill sub-blocks per partition
#define FILLB_A 2048      // 8*256 fill blocks

typedef __attribute__((ext_vector_type(8))) short short8;
typedef __attribute__((ext_vector_type(8))) unsigned short ushort8;
typedef __attribute__((ext_vector_type(4))) unsigned short ushortx4;
typedef __attribute__((ext_vector_type(4))) float f32x4;

// ---------------- runtime dtype adaptivity ----------------
// flags[0] = 1 if float inputs are fp32, 0 if bf16
// flags[1] = 1 if edge_index is int64, 0 if int32
// flags[2] = global CSR allocation cursor
static __device__ __forceinline__ float loadF(const void* p, int i, int f32) {
    if (f32) return ((const float*)p)[i];
    return __bfloat162float(((const __hip_bfloat16*)p)[i]);
}
static __device__ __forceinline__ float bfu2f(unsigned short u) {
    unsigned int t = ((unsigned int)u) << 16;
    float f;
    __builtin_memcpy(&f, &t, 4);
    return f;
}
static __device__ __forceinline__ short f2bf_s(float f) {
    union { __hip_bfloat16 b; short s; } cv;
    cv.b = __float2bfloat16(f);
    return cv.s;
}
static __device__ __forceinline__ unsigned short f2bf_u(float f) {
    union { __hip_bfloat16 b; unsigned short u; } cv;
    cv.b = __float2bfloat16(f);
    return cv.u;
}

// ---- weight prep: [block 0] dtype detect -> flags; [1..64] transpose weights
// (self-detected float dtype); [65..260] zero degi (replaces hipMemsetAsync).
__global__ void k_wprep(const void* __restrict__ W1, const void* __restrict__ Wmu,
                        const void* __restrict__ Wls, const unsigned short* __restrict__ xs,
                        const void* __restrict__ ei, __hip_bfloat16* __restrict__ Wt1,
                        __hip_bfloat16* __restrict__ Wt2, int* __restrict__ flags,
                        int* __restrict__ degi) {
    int b = blockIdx.x;
    int t = threadIdx.x;
    if (b == 0) {
        __shared__ int cnt[2];
        if (t < 2) cnt[t] = 0;
        __syncthreads();
        unsigned short v = xs[2 * t];
        int e = (v >> 7) & 0xff;
        int sane = (e >= 112 && e <= 133) ? 1 : 0;
        if (v == 0 || v == 0x8000) sane = 1;
        atomicAdd(&cnt[0], sane);
        atomicAdd(&cnt[1], (((const int*)ei)[2 * t + 1] != 0) ? 1 : 0);
        __syncthreads();
        if (t == 0) {
            flags[0] = (cnt[0] < 128) ? 1 : 0;  // few sane bf16 patterns => fp32
            flags[1] = (cnt[1] < 8) ? 1 : 0;    // all-zero odd slots => int64
            flags[2] = 0;                       // CSR bump-allocation cursor
        }
    } else if (b <= 64) {
        // self-detect float dtype from W1 bit patterns (sigma~0.09 => sane bf16 exps)
        __shared__ int cnt;
        if (t == 0) cnt = 0;
        __syncthreads();
        unsigned short v = ((const unsigned short*)W1)[2 * t];
        int e = (v >> 7) & 0xff;
        atomicAdd(&cnt, (e >= 100 && e <= 133) ? 1 : 0);
        __syncthreads();
        int f32 = (cnt < 128) ? 1 : 0;
        int idx = (b - 1) * 256 + t;  // 16384 total
        int n = idx >> 7, k = idx & 127;
        Wt1[idx] = __float2bfloat16(loadF(W1, k * F + n, f32));
        float v2 = (n < L) ? loadF(Wmu, k * L + n, f32) : loadF(Wls, k * L + (n - L), f32);
        Wt2[idx] = __float2bfloat16(v2);
    } else {
        int i = (b - 65) * 256 + t;
        if (i < 50048) degi[i] = 0;
    }
}

// ---- MFMA GEMM body (operand-SWAPPED): out[node][n] via mfma(Wfrag, Xfrag).
// mode 0 (conv1): UNSCALED output (isd applied per-source in agg1) — removes
// the gemm->degree dependency so gemm1 overlaps edge processing.
// mode 1 (conv2): bf16 h_pre with fused BN(scale,shift)+relu prologue, and
// PRE-SCALED epilogue (×isd[node]) — isd exists by then, so agg2 needs no
// per-source gather.
static __device__ __forceinline__ void gemm_body(int bid, const void* __restrict__ Xin,
        const __hip_bfloat16* __restrict__ Wt, const int* __restrict__ flags, int mode,
        const float* __restrict__ bnscale, const float* __restrict__ bnshift,
        const float* __restrict__ isd, unsigned short* __restrict__ outb) {
    int wave = threadIdx.x >> 6, lane = threadIdx.x & 63;
    int quad = lane >> 4, mr = lane & 15;
    int m0 = bid * 64 + wave * 16;
    int node = m0 + mr;
    int row = (node < N_NODES) ? node : N_NODES - 1;
    short8 a[4];
    if (mode == 1) {
        const unsigned short* xb = (const unsigned short*)Xin;
#pragma unroll
        for (int t = 0; t < 4; ++t) {
            int k0 = t * 32 + quad * 8;
            ushort8 raw = *(const ushort8*)(xb + row * F + k0);
            f32x4 s0 = *(const f32x4*)(bnscale + k0);
            f32x4 s1 = *(const f32x4*)(bnscale + k0 + 4);
            f32x4 h0 = *(const f32x4*)(bnshift + k0);
            f32x4 h1 = *(const f32x4*)(bnshift + k0 + 4);
            short8 av;
#pragma unroll
            for (int j = 0; j < 4; ++j)
                av[j] = f2bf_s(fmaxf(bfu2f(raw[j]) * s0[j] + h0[j], 0.f));
#pragma unroll
            for (int j = 0; j < 4; ++j)
                av[4 + j] = f2bf_s(fmaxf(bfu2f(raw[4 + j]) * s1[j] + h1[j], 0.f));
            a[t] = av;
        }
    } else if (flags[0]) {
        const float* xf = (const float*)Xin;
#pragma unroll
        for (int t = 0; t < 4; ++t) {
            int off = row * F + t * 32 + quad * 8;
            f32x4 v0 = *(const f32x4*)(xf + off);
            f32x4 v1 = *(const f32x4*)(xf + off + 4);
            short8 av;
#pragma unroll
            for (int j = 0; j < 4; ++j) av[j] = f2bf_s(v0[j]);
#pragma unroll
            for (int j = 0; j < 4; ++j) av[4 + j] = f2bf_s(v1[j]);
            a[t] = av;
        }
    } else {
        const short* xb = (const short*)Xin;
#pragma unroll
        for (int t = 0; t < 4; ++t)
            a[t] = *(const short8*)(xb + row * F + t * 32 + quad * 8);
    }
    f32x4 acc[8];
    const short* wb = (const short*)Wt;
#pragma unroll
    for (int nt = 0; nt < 8; ++nt) {
        const short* wp = wb + (nt * 16 + mr) * F + quad * 8;
        f32x4 c = {0.f, 0.f, 0.f, 0.f};
        c = __builtin_amdgcn_mfma_f32_16x16x32_bf16(*(const short8*)(wp), a[0], c, 0, 0, 0);
        c = __builtin_amdgcn_mfma_f32_16x16x32_bf16(*(const short8*)(wp + 32), a[1], c, 0, 0, 0);
        c = __builtin_amdgcn_mfma_f32_16x16x32_bf16(*(const short8*)(wp + 64), a[2], c, 0, 0, 0);
        c = __builtin_amdgcn_mfma_f32_16x16x32_bf16(*(const short8*)(wp + 96), a[3], c, 0, 0, 0);
        acc[nt] = c;
    }
    if (node < N_NODES) {
        float sd = (mode == 1) ? isd[node] : 1.0f;
        unsigned short* op = outb + node * F;
#pragma unroll
        for (int nt = 0; nt < 8; ++nt) {
            ushortx4 r;
#pragma unroll
            for (int j = 0; j < 4; ++j) r[j] = f2bf_u(acc[nt][j] * sd);
            *(ushortx4*)(op + nt * 16 + quad * 4) = r;
        }
    }
}

// ---- fused: [0..781] conv1 GEMM (unscaled; needs only Wt1+x) ||
// [782..2344] edge processing, 2 edges/thread: degree count + RANK capture,
// emitting u16 streams (all ids < 2^16, rank < maxdeg ~45). The degree
// atomic's return value IS the edge's unique slot => fill needs NO atomics.
// degi must be pre-zeroed (done by k_wprep). ----
__global__ __launch_bounds__(256) void k_edge_gemm1(
        const void* __restrict__ X, const __hip_bfloat16* __restrict__ Wt1,
        const int* __restrict__ flags, const void* __restrict__ ei,
        int* __restrict__ degi, unsigned short* __restrict__ src16,
        unsigned short* __restrict__ dst16, unsigned short* __restrict__ rank16,
        unsigned short* __restrict__ outb) {
    if (blockIdx.x < GEMM_BLOCKS) {
        gemm_body(blockIdx.x, X, Wt1, flags, 0, nullptr, nullptr, nullptr, outb);
    } else {
        // edge block: self-detect i64 from own window, then 2 edges/thread
        int t = threadIdx.x;
        int ebase = (blockIdx.x - GEMM_BLOCKS) * 512;
        __shared__ int nz;
        if (t == 0) nz = 0;
        __syncthreads();
        int e0 = ebase + t;
        if (e0 < N_EDGES) {
            int w = ((const int*)ei)[2 * e0 + 1];  // i64 high word vs i32 random id
            if (w != 0) atomicAdd(&nz, 1);
        }
        __syncthreads();
        int i64 = (nz < 8) ? 1 : 0;
#pragma unroll
        for (int k = 0; k < 2; ++k) {
            int e = ebase + k * 256 + t;
            if (e < N_EDGES) {
                int s, d;
                if (i64) {
                    s = (int)((const long long*)ei)[e];
                    d = (int)((const long long*)ei)[N_EDGES + e];
                } else {
                    s = ((const int*)ei)[e];
                    d = ((const int*)ei)[N_EDGES + e];
                }
                src16[e] = (unsigned short)s;
                dst16[e] = (unsigned short)d;
                rank16[e] = (unsigned short)atomicAdd(&degi[d], 1);
            }
        }
    }
}

// ---- single-pass offsets: in-block LDS scan + ONE atomic block-base alloc.
// Segment ORDER in csr is irrelevant (aggs use [offs, offs+deg)). ----
__global__ void k_offs_alloc(const int* __restrict__ degi, int* __restrict__ flags,
                             int* __restrict__ offs, float* __restrict__ isd) {
    __shared__ int s[256];
    __shared__ int base;
    int t = threadIdx.x;
    int i = blockIdx.x * 256 + t;
    int v = (i < N_NODES) ? degi[i] : 0;
    s[t] = v;
    __syncthreads();
    for (int o = 1; o < 256; o <<= 1) {
        int u = (t >= o) ? s[t - o] : 0;
        __syncthreads();
        s[t] += u;
        __syncthreads();
    }
    if (t == 255) base = atomicAdd(&flags[2], s[255]);
    __syncthreads();
    if (i < N_NODES) {
        offs[i] = base + s[t] - v;  // exclusive within block + dynamic base
        isd[i] = 1.0f / sqrtf((float)v + 1.0f);
    }
}

// ---- ATOMIC-FREE XCD-partitioned CSR fill: csr16[offs[d]+rank16[e]] = src16[e]
// (positions provably unique). grp = blockIdx&7 == XCD (round-robin) -> each
// XCD's L2 exclusively owns its offs slice (hot) and csr segment. ----
__global__ __launch_bounds__(256) void k_fill(
        const unsigned short* __restrict__ src16, const unsigned short* __restrict__ dst16,
        const unsigned short* __restrict__ rank16, const int* __restrict__ offs,
        unsigned short* __restrict__ csr16) {
    int grp = blockIdx.x & (NPART - 1);   // == XCD id (heuristic)
    int sub = blockIdx.x >> 3;            // 0..SUBS_F-1
    int lo = grp * PART_SZ, hi = lo + PART_SZ;
    int stride = SUBS_F * 256;
    for (int e = sub * 256 + threadIdx.x; e < N_EDGES; e += stride) {
        int d = dst16[e];
        if (d >= lo && d < hi) csr16[offs[d] + rank16[e]] = src16[e];
    }
}

__global__ __launch_bounds__(256) void k_gemm_bn(const void* __restrict__ Xin,
        const __hip_bfloat16* __restrict__ Wt, const int* __restrict__ flags,
        const float* __restrict__ bnscale, const float* __restrict__ bnshift,
        const float* __restrict__ isd, unsigned short* __restrict__ outb) {
    gemm_body(blockIdx.x, Xin, Wt, flags, 1, bnscale, bnshift, isd, outb);
}

// ---- shared aggregation core: wave=node, 4 groups of 16 lanes, each group
// owns a CONTIGUOUS quarter of the node's segment (sequential index loads,
// one 64B line per ~32 indices), 4-deep row-gather MLP.
// USE_ISD=1 (agg1): values unscaled, apply isd[s] per source + isd[node] self.
// USE_ISD=0 (agg2): values pre-scaled by the gemm epilogue, plain sums. ----
template <int USE_ISD>
static __device__ __forceinline__ void agg_accum(int node, int grp, int l16,
        const ushort8* __restrict__ vp, const unsigned short* __restrict__ csr,
        const int* __restrict__ offs, const int* __restrict__ degi,
        const float* __restrict__ isd, float acc[8]) {
#pragma unroll
    for (int j = 0; j < 8; ++j) acc[j] = 0.f;
    if (grp == 0) {
        ushort8 u = vp[node * 16 + l16];  // self loop
        if (USE_ISD) {
            float w = isd[node];
#pragma unroll
            for (int j = 0; j < 8; ++j) acc[j] = bfu2f(u[j]) * w;
        } else {
#pragma unroll
            for (int j = 0; j < 8; ++j) acc[j] = bfu2f(u[j]);
        }
    }
    int start = offs[node];
    int deg = degi[node];
    int i = start + ((deg * grp) >> 2);
    int ge = start + ((deg * (grp + 1)) >> 2);
    for (; i + 3 < ge; i += 4) {
        int s0 = csr[i], s1 = csr[i + 1], s2 = csr[i + 2], s3 = csr[i + 3];
        ushort8 u0 = vp[s0 * 16 + l16];
        ushort8 u1 = vp[s1 * 16 + l16];
        ushort8 u2 = vp[s2 * 16 + l16];
        ushort8 u3 = vp[s3 * 16 + l16];
        if (USE_ISD) {
            float w0 = isd[s0], w1 = isd[s1], w2 = isd[s2], w3 = isd[s3];
#pragma unroll
            for (int j = 0; j < 8; ++j)
                acc[j] += (bfu2f(u0[j]) * w0 + bfu2f(u1[j]) * w1) +
                          (bfu2f(u2[j]) * w2 + bfu2f(u3[j]) * w3);
        } else {
#pragma unroll
            for (int j = 0; j < 8; ++j)
                acc[j] += (bfu2f(u0[j]) + bfu2f(u1[j])) + (bfu2f(u2[j]) + bfu2f(u3[j]));
        }
    }
    for (; i < ge; ++i) {
        int s0 = csr[i];
        ushort8 u = vp[s0 * 16 + l16];
        if (USE_ISD) {
            float w0 = isd[s0];
#pragma unroll
            for (int j = 0; j < 8; ++j) acc[j] += bfu2f(u[j]) * w0;
        } else {
#pragma unroll
            for (int j = 0; j < 8; ++j) acc[j] += bfu2f(u[j]);
        }
    }
#pragma unroll
    for (int j = 0; j < 8; ++j) {
        acc[j] += __shfl_xor(acc[j], 16);
        acc[j] += __shfl_xor(acc[j], 32);
    }
}

// ---- aggregate1: h_pre[d] = isd[d]*(A'[d]isd[d] + sum A'[s]isd[s]) + b1 ----
__global__ void k_agg1(const unsigned short* __restrict__ val,
                       const unsigned short* __restrict__ csr,
                       const int* __restrict__ offs, const int* __restrict__ degi,
                       const float* __restrict__ isd, const void* __restrict__ b1,
                       const int* __restrict__ flags, unsigned short* __restrict__ out) {
    int node = blockIdx.x * 4 + (threadIdx.x >> 6);
    if (node >= N_NODES) return;
    int lane = threadIdx.x & 63;
    int grp = lane >> 4, l16 = lane & 15;
    float acc[8];
    agg_accum<1>(node, grp, l16, (const ushort8*)val, csr, offs, degi, isd, acc);
    if (grp == 0) {
        float sd = isd[node];
        int c0 = l16 * 8, f32 = flags[0];
        ushort8 r;
#pragma unroll
        for (int j = 0; j < 8; ++j) r[j] = f2bf_u(acc[j] * sd + loadF(b1, c0 + j, f32));
        ((ushort8*)out)[node * 16 + l16] = r;
    }
}

// ---- BN stats phase 1: per-block column sums / sum-of-squares (no atomics) ----
__global__ void k_bnstats(const unsigned short* __restrict__ h, float* __restrict__ partial) {
    __shared__ float ls[256][8];
    __shared__ float lq[256][8];
    int t = threadIdx.x;
    int o = t & 15, rg = t >> 4;
    int row0 = blockIdx.x * 128 + rg;
    float s[8] = {0.f}, q[8] = {0.f};
#pragma unroll
    for (int i = 0; i < 8; ++i) {
        int row = row0 + i * 16;
        if (row < N_NODES) {
            ushort8 u = *(const ushort8*)(h + row * F + o * 8);
#pragma unroll
            for (int j = 0; j < 8; ++j) {
                float v = bfu2f(u[j]);
                s[j] += v;
                q[j] += v * v;
            }
        }
    }
#pragma unroll
    for (int j = 0; j < 8; ++j) { ls[t][j] = s[j]; lq[t][j] = q[j]; }
    __syncthreads();
    if (t < 128) {
        int c = t, oo = c >> 3, jj = c & 7;
        float ts = 0.f, tq = 0.f;
#pragma unroll
        for (int rgi = 0; rgi < 16; ++rgi) {
            ts += ls[rgi * 16 + oo][jj];
            tq += lq[rgi * 16 + oo][jj];
        }
        partial[blockIdx.x * 256 + c] = ts;
        partial[blockIdx.x * 256 + 128 + c] = tq;
    }
}

// ---- fused BN reduce + coefficient prep: block c -> scale[c], shift[c] ----
__global__ void k_bnredprep(const float* __restrict__ partial, const void* __restrict__ gamma,
                            const void* __restrict__ beta, const int* __restrict__ flags,
                            float* __restrict__ scale, float* __restrict__ shift) {
    int c = blockIdx.x;  // 0..127
    float s = 0.f, q = 0.f;
    for (int b = threadIdx.x; b < BN_BLOCKS; b += 256) {
        s += partial[b * 256 + c];
        q += partial[b * 256 + 128 + c];
    }
#pragma unroll
    for (int o = 32; o; o >>= 1) {
        s += __shfl_down(s, o);
        q += __shfl_down(q, o);
    }
    __shared__ float ws[4], wq[4];
    if ((threadIdx.x & 63) == 0) {
        ws[threadIdx.x >> 6] = s;
        wq[threadIdx.x >> 6] = q;
    }
    __syncthreads();
    if (threadIdx.x == 0) {
        float S = ws[0] + ws[1] + ws[2] + ws[3];
        float Q = wq[0] + wq[1] + wq[2] + wq[3];
        const float invN = 1.0f / (float)N_NODES;
        float m = S * invN;
        float var = Q * invN - m * m;
        int f32 = flags[0];
        float sc = loadF(gamma, c, f32) * rsqrtf(var + BN_EPS);
        scale[c] = sc;
        shift[c] = loadF(beta, c, f32) - m * sc;
    }
}

// ---- aggregate2 + epilogue: values pre-scaled by gemm_bn; write
// mu[N,64] ++ log_std[N,64] in output dtype. ----
__global__ void k_agg2(const unsigned short* __restrict__ val,
                       const unsigned short* __restrict__ csr,
                       const int* __restrict__ offs, const int* __restrict__ degi,
                       const float* __restrict__ isd, const void* __restrict__ bmu,
                       const void* __restrict__ bls, const int* __restrict__ flags,
                       void* __restrict__ out) {
    int node = blockIdx.x * 4 + (threadIdx.x >> 6);
    if (node >= N_NODES) return;
    int lane = threadIdx.x & 63;
    int grp = lane >> 4, l16 = lane & 15;
    float acc[8];
    agg_accum<0>(node, grp, l16, (const ushort8*)val, csr, offs, degi, isd, acc);
    if (grp == 0) {
        float sd = isd[node];
        int c0 = l16 * 8, f32 = flags[0];
        int hsel = (c0 >= L) ? 1 : 0;
        int cc = c0 - hsel * L;
        const void* bp = hsel ? bls : bmu;
        float o8[8];
#pragma unroll
        for (int j = 0; j < 8; ++j) o8[j] = acc[j] * sd + loadF(bp, cc + j, f32);
        long base_o = (long)hsel * (N_NODES * 64) + (long)node * 64 + cc;
        if (f32) {
            f32x4 r0 = {o8[0], o8[1], o8[2], o8[3]};
            f32x4 r1 = {o8[4], o8[5], o8[6], o8[7]};
            __builtin_nontemporal_store(r0, (f32x4*)((float*)out + base_o));
            __builtin_nontemporal_store(r1, (f32x4*)((float*)out + base_o + 4));
        } else {
            ushort8 r;
#pragma unroll
            for (int j = 0; j < 8; ++j) r[j] = f2bf_u(o8[j]);
            __builtin_nontemporal_store(r, (ushort8*)((__hip_bfloat16*)out + base_o));
        }
    }
}

extern "C" void kernel_launch(void* const* d_in, const int* in_sizes, int n_in,
                              void* d_out, int out_size, void* d_ws, size_t ws_size,
                              hipStream_t stream) {
    const void* x     = d_in[0];
    const void* ei    = d_in[1];
    const void* W1    = d_in[2];
    const void* b1    = d_in[3];
    const void* gamma = d_in[4];
    const void* beta  = d_in[5];
    const void* Wmu   = d_in[6];
    const void* bmu   = d_in[7];
    const void* Wls   = d_in[8];
    const void* bls   = d_in[9];

    int*   degi  = (int*)d_ws;                     // [50048] degrees
    int*   offs  = degi + 50048;                   // [50048] exclusive starts
    float* isd   = (float*)(offs + 50048);         // [50048]
    float* stats = isd + 50048;                    // scale[128] shift[128] (+pad)
    int*   flags = (int*)(stats + 512);            // [16] (flags[2]=alloc cursor)
    unsigned short* csr16  = (unsigned short*)(flags + 16);  // [800000] u16
    unsigned short* src16  = csr16 + 800000;                 // [800000] u16
    unsigned short* dst16  = src16 + 800000;                 // [800000] u16
    unsigned short* rank16 = dst16 + 800000;                 // [800000] u16
    __hip_bfloat16* Wt1 = (__hip_bfloat16*)(rank16 + 800000);// [16384]
    __hip_bfloat16* Wt2 = Wt1 + 16384;                       // [16384]
    unsigned short* Abf = (unsigned short*)(Wt2 + 16384);    // [N*128] bf16 A'
    unsigned short* Hpre = Abf + N_NODES * F;                // [N*128] bf16 h_pre
    float* partial = (float*)(Hpre + N_NODES * F);           // [BN_BLOCKS*256]

    const int NT = 256;
    const int AGG_BLOCKS = (N_NODES + 3) / 4;

    // flags + weight transpose + degi zero (one kernel)
    k_wprep<<<65 + SCAN_BLOCKS, NT, 0, stream>>>(W1, Wmu, Wls, (const unsigned short*)x,
                                                 ei, Wt1, Wt2, flags, degi);
    // conv1 GEMM (unscaled, needs only Wt1) || edge degree/rank/u16-convert
    k_edge_gemm1<<<GEMM_BLOCKS + EDGE_BLOCKS2, NT, 0, stream>>>(
        x, Wt1, flags, ei, degi, src16, dst16, rank16, Abf);
    // single-pass offsets via atomic block-base allocation
    k_offs_alloc<<<SCAN_BLOCKS, NT, 0, stream>>>(degi, flags, offs, isd);
    // atomic-free XCD-partitioned CSR fill (u16 streams)
    k_fill<<<FILLB_A, NT, 0, stream>>>(src16, dst16, rank16, offs, csr16);
    // aggregate conv1 + per-source isd + bias
    k_agg1<<<AGG_BLOCKS, NT, 0, stream>>>(Abf, csr16, offs, degi, isd, b1, flags, Hpre);
    // batchnorm stats (2-phase, no atomics) + fused reduce/prep
    k_bnstats<<<BN_BLOCKS, NT, 0, stream>>>(Hpre, partial);
    k_bnredprep<<<128, NT, 0, stream>>>(partial, gamma, beta, flags, stats, stats + 128);
    // conv2: A'2 = (relu(bn(h_pre)) @ [Wmu|Wls])*isd -> bf16 pre-scaled
    k_gemm_bn<<<GEMM_BLOCKS, NT, 0, stream>>>(Hpre, Wt2, flags, stats, stats + 128,
                                              isd, Abf);
    // aggregate conv2 (plain sums) + epilogue
    k_agg2<<<AGG_BLOCKS, NT, 0, stream>>>(Abf, csr16, offs, degi, isd, bmu, bls, flags, d_out);
}